// Round 6
// baseline (374.255 us; speedup 1.0000x reference)
//
#include <hip/hip_runtime.h>

typedef unsigned short u16;
typedef unsigned int   u32;

#define BATCH 4
#define SEQ   8192
#define DIM   1024
#define FL    2048
#define TROW  10240   // padded time row: max read t0+Tw+2144+31 = 10239

// r6 geometry: barrier-free, direct-from-L2 B reads (no X staging).
#define BM 512        // time rows per block (4 waves x 128 t-rows)
#define BN 64         // dims per block
#define NSTEP 68      // kk = Tw + s*32, s=0..67: covers k in [Tw, Tw+2175] >= Tw+2174 needed
#define WOFF 64       // W[w][j] = filt[w - WOFF + j]
#define NW   2272     // windows: read range [33, 2262]

typedef float  f32x4  __attribute__((ext_vector_type(4)));
typedef __bf16 bf16x8 __attribute__((ext_vector_type(8)));
typedef short  s16x8  __attribute__((ext_vector_type(8)));

__device__ __forceinline__ u16 f2bf(float f) {
  u32 u = __float_as_uint(f);
  u += 0x7fffu + ((u >> 16) & 1u);   // round-to-nearest-even
  return (u16)(u >> 16);
}

// ---- pass 1: x[b][t][d] fp32 -> xT[b][d][t] bf16, zero-padded for t in [SEQ, TROW)
__global__ __launch_bounds__(256) void k_transpose(const float* __restrict__ x,
                                                   u16* __restrict__ xT) {
  __shared__ __align__(16) u16 sm[64 * 66];   // [t][d], stride 66 breaks bank conflicts
  const int bid = blockIdx.x;
  const int tb = bid % (TROW / 64);
  const int db = (bid / (TROW / 64)) % (DIM / 64);
  const int b  = bid / ((TROW / 64) * (DIM / 64));
  const int t0 = tb * 64, d0 = db * 64;
  const int tid = threadIdx.x;

  // load: 16 threads x float4 cover one 64-wide d row; 16 t-rows per sweep
  const int c4 = tid & 15;
  const int lt = tid >> 4;
  const float* xb = x + (size_t)b * SEQ * DIM + d0 + c4 * 4;
  #pragma unroll
  for (int s = 0; s < 64; s += 16) {
    const int tl = lt + s;
    const int t = t0 + tl;
    float4 v = make_float4(0.f, 0.f, 0.f, 0.f);
    if (t < SEQ) v = *(const float4*)(xb + (size_t)t * DIM);
    u32 p0 = (u32)f2bf(v.x) | ((u32)f2bf(v.y) << 16);
    u32 p1 = (u32)f2bf(v.z) | ((u32)f2bf(v.w) << 16);
    u32* dst = (u32*)&sm[tl * 66 + c4 * 4];
    dst[0] = p0;
    dst[1] = p1;
  }
  __syncthreads();
  // store: lane packs 8 consecutive t (16 B) per d row -> dwordx4 stores.
  const int q  = tid & 7;
  const int dl = tid >> 3;   // 0..31
  u16* xo = xT + ((size_t)b * DIM + d0) * TROW + t0 + 8 * q;
  #pragma unroll
  for (int s = 0; s < 2; ++s) {
    const int d = dl + 32 * s;
    u32 w[4];
    #pragma unroll
    for (int h = 0; h < 4; ++h) {
      w[h] = (u32)sm[(8 * q + 2 * h) * 66 + d] |
             ((u32)sm[(8 * q + 2 * h + 1) * 66 + d] << 16);
    }
    *(uint4*)(xo + (size_t)d * TROW) = *(const uint4*)w;
  }
}

// ---- pass 2: banded-Toeplitz MFMA conv, BARRIER-FREE.
// Out[t,d] = sum_k filt[k-t] * x[k,d].  A = Toeplitz (M=t), B = xT (N=d), K = k.
// Wave: 128(t) x 64(d) = 8 m-tiles x 4 n-tiles of 16x16x32 MFMA.
// Rolling A: A(mt)@step == A(mt-2)@(step-1) -> only 2 Wb LDS reads per 32 MFMAs.
//
// r6 RATIONALE: r0-r5 tried prefetch depth / phasing / occupancy / counted
// vmcnt; k_conv stayed 138-154 us (MfmaUtil ~43% == 58us-of-MFMA / time,
// i.e. it just restates dur). The pin is the staging STRUCTURE: the
// global->LDS->barrier->ds_read round trip couples 4 waves across 4 SIMDs
// every 64 k (convoy on the slowest wave) and the vmcnt(0)-drain before each
// s_barrier exposes load latency per stage. But xT is 84 MB: it FITS IN L3
// (256 MB), and consecutive t-blocks overlap ~90% in k -> staged data was
// already L2/L3-resident (FETCH 164 MB << 604 MB staged). Catalog
// common-mistake #7: don't LDS-stage data that cache-fits.
// So: B-fragments load DIRECTLY global->register. Each lane's B-frag is one
// 16B global_load_dwordx4: xT[d0+nt*16+lq][t0+Tw+quad*8+s*32 .. +8] --
// identical fragment content to the staged path. NO barrier in the k-loop;
// waves free-run, latency hidden by 1-step register prefetch + 2 waves/SIMD.
// LDS holds only Wb (35.5 KB). ~220 VGPR -> 2 waves/SIMD (reg-capped).
__global__ __launch_bounds__(256, 2) void k_conv(const u16* __restrict__ xT,
                                                 const float* __restrict__ filt,
                                                 float* __restrict__ out) {
  __shared__ __align__(16) u16 Wb[NW * 8];   // filter windows, 35.5 KB

  const int bid = blockIdx.x;
  const int tb = bid & 15;
  const int db = (bid >> 4) & 15;
  const int b  = bid >> 8;
  const int t0 = tb * BM;
  const int d0 = db * BN;

  const int tid  = threadIdx.x;
  const int wid  = tid >> 6;    // 0..3
  const int lane = tid & 63;
  const int quad = lane >> 4;
  const int lq   = lane & 15;
  const int Tw   = wid * 128;   // wave's time base within block

  // build filter windows: Wb[w][j] = bf16(filt[w - WOFF + j]), zeros outside [0,FL)
  for (int w = tid; w < NW; w += 256) {
    const int base = w - WOFF;
    u32 pk[4];
    #pragma unroll
    for (int h = 0; h < 4; ++h) {
      const int i0 = base + 2 * h;
      const int i1 = i0 + 1;
      const float v0 = (i0 >= 0 && i0 < FL) ? filt[i0] : 0.f;
      const float v1 = (i1 >= 0 && i1 < FL) ? filt[i1] : 0.f;
      pk[h] = (u32)f2bf(v0) | ((u32)f2bf(v1) << 16);
    }
    u32* dst = (u32*)&Wb[w * 8];
    dst[0] = pk[0]; dst[1] = pk[1]; dst[2] = pk[2]; dst[3] = pk[3];
  }
  __syncthreads();   // the ONLY barrier: Wb ready; k-loop is barrier-free

  // per-lane B pointers: row d = d0 + nt*16 + lq, t base = t0 + Tw + quad*8.
  // step s advances k by 32 elements (64 B). Max t touched:
  // t0+Tw+67*32+24+7 = 7680+384+2144+31 = 10239 < TROW. OK.
  const u16* pB0 = xT + ((size_t)b * DIM + d0 + 0 * 16 + lq) * TROW + t0 + Tw + quad * 8;
  const u16* pB1 = pB0 + (size_t)16 * TROW;
  const u16* pB2 = pB1 + (size_t)16 * TROW;
  const u16* pB3 = pB2 + (size_t)16 * TROW;

  f32x4 acc[8][4];
  const f32x4 fz = {0.f, 0.f, 0.f, 0.f};
  #pragma unroll
  for (int i = 0; i < 8; ++i)
    #pragma unroll
    for (int j = 0; j < 4; ++j) acc[i][j] = fz;

  const s16x8 sz = {0, 0, 0, 0, 0, 0, 0, 0};
  bf16x8 roll0 = __builtin_bit_cast(bf16x8, sz);
  bf16x8 roll1 = roll0, roll2 = roll0, roll3 = roll0, roll4 = roll0, roll5 = roll0;

  // A-window index: w0 = s*32 + wbase; at s=0, rolls correspond to windows
  // left of the filter (all-zero rows in Wb) -> zero-init is exact.
  const int wbase = quad * 8 - lq + WOFF;

  // one compute step (32 k): 2 Wb reads + 32 MFMAs + roll shift
#define CONV_STEP(B0, B1, B2, B3, S)                                                   \
  do {                                                                                 \
    const int w0_ = (S) * 32 + wbase;                                                  \
    const bf16x8 a0_ = *(const bf16x8*)&Wb[w0_ * 8];                                   \
    const bf16x8 a1_ = *(const bf16x8*)&Wb[(w0_ - 16) * 8];                            \
    __builtin_amdgcn_s_setprio(1);                                                     \
    acc[0][0] = __builtin_amdgcn_mfma_f32_16x16x32_bf16(a0_,   B0, acc[0][0], 0, 0, 0);\
    acc[1][0] = __builtin_amdgcn_mfma_f32_16x16x32_bf16(a1_,   B0, acc[1][0], 0, 0, 0);\
    acc[2][0] = __builtin_amdgcn_mfma_f32_16x16x32_bf16(roll0, B0, acc[2][0], 0, 0, 0);\
    acc[3][0] = __builtin_amdgcn_mfma_f32_16x16x32_bf16(roll1, B0, acc[3][0], 0, 0, 0);\
    acc[4][0] = __builtin_amdgcn_mfma_f32_16x16x32_bf16(roll2, B0, acc[4][0], 0, 0, 0);\
    acc[5][0] = __builtin_amdgcn_mfma_f32_16x16x32_bf16(roll3, B0, acc[5][0], 0, 0, 0);\
    acc[6][0] = __builtin_amdgcn_mfma_f32_16x16x32_bf16(roll4, B0, acc[6][0], 0, 0, 0);\
    acc[7][0] = __builtin_amdgcn_mfma_f32_16x16x32_bf16(roll5, B0, acc[7][0], 0, 0, 0);\
    acc[0][1] = __builtin_amdgcn_mfma_f32_16x16x32_bf16(a0_,   B1, acc[0][1], 0, 0, 0);\
    acc[1][1] = __builtin_amdgcn_mfma_f32_16x16x32_bf16(a1_,   B1, acc[1][1], 0, 0, 0);\
    acc[2][1] = __builtin_amdgcn_mfma_f32_16x16x32_bf16(roll0, B1, acc[2][1], 0, 0, 0);\
    acc[3][1] = __builtin_amdgcn_mfma_f32_16x16x32_bf16(roll1, B1, acc[3][1], 0, 0, 0);\
    acc[4][1] = __builtin_amdgcn_mfma_f32_16x16x32_bf16(roll2, B1, acc[4][1], 0, 0, 0);\
    acc[5][1] = __builtin_amdgcn_mfma_f32_16x16x32_bf16(roll3, B1, acc[5][1], 0, 0, 0);\
    acc[6][1] = __builtin_amdgcn_mfma_f32_16x16x32_bf16(roll4, B1, acc[6][1], 0, 0, 0);\
    acc[7][1] = __builtin_amdgcn_mfma_f32_16x16x32_bf16(roll5, B1, acc[7][1], 0, 0, 0);\
    acc[0][2] = __builtin_amdgcn_mfma_f32_16x16x32_bf16(a0_,   B2, acc[0][2], 0, 0, 0);\
    acc[1][2] = __builtin_amdgcn_mfma_f32_16x16x32_bf16(a1_,   B2, acc[1][2], 0, 0, 0);\
    acc[2][2] = __builtin_amdgcn_mfma_f32_16x16x32_bf16(roll0, B2, acc[2][2], 0, 0, 0);\
    acc[3][2] = __builtin_amdgcn_mfma_f32_16x16x32_bf16(roll1, B2, acc[3][2], 0, 0, 0);\
    acc[4][2] = __builtin_amdgcn_mfma_f32_16x16x32_bf16(roll2, B2, acc[4][2], 0, 0, 0);\
    acc[5][2] = __builtin_amdgcn_mfma_f32_16x16x32_bf16(roll3, B2, acc[5][2], 0, 0, 0);\
    acc[6][2] = __builtin_amdgcn_mfma_f32_16x16x32_bf16(roll4, B2, acc[6][2], 0, 0, 0);\
    acc[7][2] = __builtin_amdgcn_mfma_f32_16x16x32_bf16(roll5, B2, acc[7][2], 0, 0, 0);\
    acc[0][3] = __builtin_amdgcn_mfma_f32_16x16x32_bf16(a0_,   B3, acc[0][3], 0, 0, 0);\
    acc[1][3] = __builtin_amdgcn_mfma_f32_16x16x32_bf16(a1_,   B3, acc[1][3], 0, 0, 0);\
    acc[2][3] = __builtin_amdgcn_mfma_f32_16x16x32_bf16(roll0, B3, acc[2][3], 0, 0, 0);\
    acc[3][3] = __builtin_amdgcn_mfma_f32_16x16x32_bf16(roll1, B3, acc[3][3], 0, 0, 0);\
    acc[4][3] = __builtin_amdgcn_mfma_f32_16x16x32_bf16(roll2, B3, acc[4][3], 0, 0, 0);\
    acc[5][3] = __builtin_amdgcn_mfma_f32_16x16x32_bf16(roll3, B3, acc[5][3], 0, 0, 0);\
    acc[6][3] = __builtin_amdgcn_mfma_f32_16x16x32_bf16(roll4, B3, acc[6][3], 0, 0, 0);\
    acc[7][3] = __builtin_amdgcn_mfma_f32_16x16x32_bf16(roll5, B3, acc[7][3], 0, 0, 0);\
    __builtin_amdgcn_s_setprio(0);                                                     \
    roll5 = roll3; roll4 = roll2; roll3 = roll1; roll2 = roll0;                        \
    roll1 = a1_;   roll0 = a0_;                                                        \
  } while (0)

  // software-pipelined k-loop, unroll 2 (NSTEP=68 even), no barriers:
  // prefetch step s+1 into the idle register set while computing step s.
  bf16x8 bA0 = *(const bf16x8*)(pB0);
  bf16x8 bA1 = *(const bf16x8*)(pB1);
  bf16x8 bA2 = *(const bf16x8*)(pB2);
  bf16x8 bA3 = *(const bf16x8*)(pB3);
  bf16x8 bB0, bB1, bB2, bB3;

  for (int s = 0; s < NSTEP; s += 2) {
    bB0 = *(const bf16x8*)(pB0 + (s + 1) * 32);
    bB1 = *(const bf16x8*)(pB1 + (s + 1) * 32);
    bB2 = *(const bf16x8*)(pB2 + (s + 1) * 32);
    bB3 = *(const bf16x8*)(pB3 + (s + 1) * 32);
    CONV_STEP(bA0, bA1, bA2, bA3, s);
    if (s + 2 < NSTEP) {
      bA0 = *(const bf16x8*)(pB0 + (s + 2) * 32);
      bA1 = *(const bf16x8*)(pB1 + (s + 2) * 32);
      bA2 = *(const bf16x8*)(pB2 + (s + 2) * 32);
      bA3 = *(const bf16x8*)(pB3 + (s + 2) * 32);
    }
    CONV_STEP(bB0, bB1, bB2, bB3, s + 1);
  }
#undef CONV_STEP

  // epilogue: C/D layout col = lane&15 (d), row = quad*4 + reg (t)
  float* ob = out + ((size_t)b * SEQ + t0 + Tw) * DIM + d0;
  #pragma unroll
  for (int mt = 0; mt < 8; ++mt) {
    #pragma unroll
    for (int nt = 0; nt < 4; ++nt) {
      #pragma unroll
      for (int r = 0; r < 4; ++r) {
        ob[(size_t)(mt * 16 + quad * 4 + r) * DIM + nt * 16 + lq] = acc[mt][nt][r];
      }
    }
  }
}

extern "C" void kernel_launch(void* const* d_in, const int* in_sizes, int n_in,
                              void* d_out, int out_size, void* d_ws, size_t ws_size,
                              hipStream_t stream) {
  const float* x    = (const float*)d_in[0];
  const float* filt = (const float*)d_in[1];
  float* out = (float*)d_out;
  u16* xT = (u16*)d_ws;   // needs 4*1024*10240*2 = 83.9 MB of workspace
  (void)in_sizes; (void)n_in; (void)out_size; (void)ws_size;

  k_transpose<<<BATCH * (TROW / 64) * (DIM / 64), 256, 0, stream>>>(x, xT);
  k_conv<<<BATCH * 16 * 16, 256, 0, stream>>>(xT, filt, out);
}